// Round 5
// baseline (219.905 us; speedup 1.0000x reference)
//
#include <hip/hip_runtime.h>
#include <hip/hip_bf16.h>
#include <string.h>

// Problem constants (B=2, S=2048, D=1024, H=16, hd=64)
#define BB 2
#define SS 2048
#define DD 1024
#define NH 16
#define TT (BB * SS)       // 4096 rows total
#define N3 (3 * DD)        // 3072
#define A_SIZE (TT * DD)                  // 4194304 floats (output "a")
#define PRESENT_HALF (BB * NH * SS * 64)  // 4194304 floats per k/v half
#define C2Q 0.18033688011112043f          // log2(e)/8, folded into q in gemm1 epilogue

typedef __attribute__((ext_vector_type(8))) short short8;
typedef __attribute__((ext_vector_type(4))) float floatx4;
typedef __attribute__((ext_vector_type(8))) unsigned short ushort8;

__device__ __forceinline__ unsigned short f2bf(float f) {
    union { float f; unsigned u; } v; v.f = f;
    unsigned r = v.u + 0x7fffu + ((v.u >> 16) & 1u);
    return (unsigned short)(r >> 16);
}
__device__ __forceinline__ unsigned pack2bf(float a, float b) {
    __hip_bfloat162 h = __float22bfloat162_rn(float2{a, b});
    unsigned u; memcpy(&u, &h, 4); return u;
}
__device__ __forceinline__ float bf2f(unsigned short u) {
    union { unsigned u; float f; } v; v.u = ((unsigned)u) << 16; return v.f;
}

// async global->LDS, 16B per lane. lds base must be WAVE-UNIFORM; lane i lands at lds + i*16.
__device__ __forceinline__ void async16(const unsigned short* g, unsigned short* lds) {
    __builtin_amdgcn_global_load_lds(
        (const __attribute__((address_space(1))) unsigned int*)g,
        (__attribute__((address_space(3))) unsigned int*)lds,
        16, 0, 0);
}

// ---------------- fused prep: cast x + transpose both weights ----------------
__device__ __forceinline__ void transpose_tile(const float* __restrict__ src,
                                               unsigned short* __restrict__ dst,
                                               int R, int C, int bx, int by, int tid) {
    __shared__ float tile[32][33];
    int c0 = bx * 32, r0 = by * 32;
    int tx = tid & 31, ty = tid >> 5;
    for (int i = ty; i < 32; i += 8)
        tile[i][tx] = src[(size_t)(r0 + i) * C + c0 + tx];
    __syncthreads();
    for (int i = ty; i < 32; i += 8)
        dst[(size_t)(c0 + i) * R + r0 + tx] = f2bf(tile[tx][i]);
}

__global__ __launch_bounds__(256)
void prep_kernel(const float* __restrict__ x,
                 const float* __restrict__ wa,
                 const float* __restrict__ wp,
                 unsigned short* __restrict__ xb,
                 unsigned short* __restrict__ wqkvt,
                 unsigned short* __restrict__ wprojt) {
    int bid = blockIdx.x, tid = threadIdx.x;
    if (bid < 2048) {                       // cast x: 4096x1024 fp32 -> bf16
        int i = (bid * 256 + tid) * 8;
        float4 a = *(const float4*)(x + i);
        float4 b = *(const float4*)(x + i + 4);
        ushort8 o;
        o[0] = f2bf(a.x); o[1] = f2bf(a.y); o[2] = f2bf(a.z); o[3] = f2bf(a.w);
        o[4] = f2bf(b.x); o[5] = f2bf(b.y); o[6] = f2bf(b.z); o[7] = f2bf(b.w);
        *(ushort8*)(xb + i) = o;
    } else if (bid < 2048 + 3072) {         // c_attn_w (1024x3072) -> wqkvt (3072x1024)
        int b2 = bid - 2048;
        transpose_tile(wa, wqkvt, DD, N3, b2 % 96, b2 / 96, tid);
    } else {                                // c_proj_w (1024x1024) -> wprojt (1024x1024)
        int b3 = bid - 5120;
        transpose_tile(wp, wprojt, DD, DD, b3 & 31, b3 >> 5, tid);
    }
}

// ---------------- kv_aux: present (fp32) + vT in one pass over k/v ----------------
__global__ __launch_bounds__(256)
void kv_aux_kernel(const unsigned short* __restrict__ qkvb,
                   float* __restrict__ out,
                   unsigned short* __restrict__ vT) {
    __shared__ unsigned short tile[64][72];
    const int bh = blockIdx.x, st = blockIdx.y;
    const int b = bh >> 4, h = bh & 15;
    const int tid = threadIdx.x;
    const int r = tid >> 2, c = (tid & 3) * 16;
    const int s = st * 64 + r;

    const unsigned short* kp = qkvb + ((size_t)(b * SS + s)) * 3072 + 1024 + h * 64 + c;
    ushort8 k0 = *(const ushort8*)(kp);
    ushort8 k1 = *(const ushort8*)(kp + 8);
    ushort8 v0 = *(const ushort8*)(kp + 1024);
    ushort8 v1 = *(const ushort8*)(kp + 1032);

    float* pk = out + A_SIZE + (((size_t)(b * NH + h) * SS + s) * 64 + c);
    *(float4*)(pk)      = float4{bf2f(k0[0]), bf2f(k0[1]), bf2f(k0[2]), bf2f(k0[3])};
    *(float4*)(pk + 4)  = float4{bf2f(k0[4]), bf2f(k0[5]), bf2f(k0[6]), bf2f(k0[7])};
    *(float4*)(pk + 8)  = float4{bf2f(k1[0]), bf2f(k1[1]), bf2f(k1[2]), bf2f(k1[3])};
    *(float4*)(pk + 12) = float4{bf2f(k1[4]), bf2f(k1[5]), bf2f(k1[6]), bf2f(k1[7])};
    float* pv = pk + PRESENT_HALF;
    *(float4*)(pv)      = float4{bf2f(v0[0]), bf2f(v0[1]), bf2f(v0[2]), bf2f(v0[3])};
    *(float4*)(pv + 4)  = float4{bf2f(v0[4]), bf2f(v0[5]), bf2f(v0[6]), bf2f(v0[7])};
    *(float4*)(pv + 8)  = float4{bf2f(v1[0]), bf2f(v1[1]), bf2f(v1[2]), bf2f(v1[3])};
    *(float4*)(pv + 12) = float4{bf2f(v1[4]), bf2f(v1[5]), bf2f(v1[6]), bf2f(v1[7])};

    // vT[(bh*64+d)][s] transpose via LDS
    *(ushort8*)(&tile[r][c])     = v0;
    *(ushort8*)(&tile[r][c + 8]) = v1;
    __syncthreads();
    int d = tid >> 2, s0 = (tid & 3) * 16;
    unsigned short tmp[16];
    for (int e = 0; e < 16; ++e) tmp[e] = tile[s0 + e][d];
    unsigned short* dst = vT + ((size_t)bh * 64 + d) * SS + st * 64 + s0;
    *(int4*)(dst)     = *(const int4*)(tmp);
    *(int4*)(dst + 8) = *(const int4*)(tmp + 8);
}

// ---------------- bf16 GEMM1 (128x128), single-barrier double-buffered ----------------
// qkv = xb @ wqkvt^T + bias -> bf16 [t][3072]; q-columns pre-scaled by C2Q.
__global__ __launch_bounds__(256)
void gemm1_kernel(const unsigned short* __restrict__ A,
                  const unsigned short* __restrict__ Bt,
                  const float* __restrict__ bias,
                  unsigned short* __restrict__ out_bf) {
    __shared__ unsigned short As[2][128][32];
    __shared__ unsigned short Bs[2][128][32];
    const int tid  = threadIdx.x;
    const int t0   = blockIdx.y * 128;
    const int n0   = blockIdx.x * 128;
    const int wave = tid >> 6, lane = tid & 63;
    const int wm = wave >> 1, wn = wave & 1;
    const int l15 = lane & 15, quad = lane >> 4;
    const int sr = lane >> 2, sc = (lane & 3) * 8;

    floatx4 acc[4][4];
    for (int i = 0; i < 4; ++i)
        for (int j = 0; j < 4; ++j)
            for (int e = 0; e < 4; ++e) acc[i][j][e] = 0.f;

    const unsigned short* gA = A  + (size_t)(t0 + wave * 32 + sr) * 1024 + sc;
    const unsigned short* gB = Bt + (size_t)(n0 + wave * 32 + sr) * 1024 + sc;

    async16(gA,             &As[0][wave * 32][0]);
    async16(gA + 16 * 1024, &As[0][wave * 32 + 16][0]);
    async16(gB,             &Bs[0][wave * 32][0]);
    async16(gB + 16 * 1024, &Bs[0][wave * 32 + 16][0]);

    for (int kt = 0; kt < 32; ++kt) {
        const int cur = kt & 1;
        __syncthreads();
        if (kt < 31) {
            const int k1 = (kt + 1) * 32;
            async16(gA + k1,             &As[cur ^ 1][wave * 32][0]);
            async16(gA + k1 + 16 * 1024, &As[cur ^ 1][wave * 32 + 16][0]);
            async16(gB + k1,             &Bs[cur ^ 1][wave * 32][0]);
            async16(gB + k1 + 16 * 1024, &Bs[cur ^ 1][wave * 32 + 16][0]);
        }
        short8 af[4], bfr[4];
        for (int mt = 0; mt < 4; ++mt)
            af[mt] = *(const short8*)(&As[cur][wm * 64 + mt * 16 + l15][quad * 8]);
        for (int nt = 0; nt < 4; ++nt)
            bfr[nt] = *(const short8*)(&Bs[cur][wn * 64 + nt * 16 + l15][quad * 8]);
        for (int mt = 0; mt < 4; ++mt)
            for (int nt = 0; nt < 4; ++nt)   // swapped operands: acc = C^T fragments
                acc[mt][nt] = __builtin_amdgcn_mfma_f32_16x16x32_bf16(bfr[nt], af[mt], acc[mt][nt], 0, 0, 0);
    }

    const float qs = (n0 < 1024) ? C2Q : 1.0f;
    for (int mt = 0; mt < 4; ++mt) {
        const int t = t0 + wm * 64 + mt * 16 + l15;
        unsigned short* po = out_bf + (size_t)t * 3072 + n0 + wn * 64;
        for (int nt = 0; nt < 4; ++nt) {
            float4 b4 = *(const float4*)(bias + n0 + wn * 64 + nt * 16 + quad * 4);
            uint2 w = {pack2bf((acc[mt][nt][0] + b4.x) * qs, (acc[mt][nt][1] + b4.y) * qs),
                       pack2bf((acc[mt][nt][2] + b4.z) * qs, (acc[mt][nt][3] + b4.w) * qs)};
            *(uint2*)(po + nt * 16 + quad * 4) = w;
        }
    }
}

// ---------------- bf16 GEMM2 (128x64 tile -> 512 blocks, 2/CU) ----------------
__global__ __launch_bounds__(256)
void gemm2_kernel(const unsigned short* __restrict__ A,
                  const unsigned short* __restrict__ Bt,
                  const float* __restrict__ bias,
                  float* __restrict__ out_f) {
    __shared__ unsigned short As[2][128][32];
    __shared__ unsigned short Bs[2][64][32];
    const int tid  = threadIdx.x;
    const int t0   = blockIdx.y * 128;
    const int n0   = blockIdx.x * 64;
    const int wave = tid >> 6, lane = tid & 63;
    const int wm = wave >> 1, wn = wave & 1;
    const int l15 = lane & 15, quad = lane >> 4;
    const int sr = lane >> 2, sc = (lane & 3) * 8;

    floatx4 acc[4][2];
    for (int i = 0; i < 4; ++i)
        for (int j = 0; j < 2; ++j)
            for (int e = 0; e < 4; ++e) acc[i][j][e] = 0.f;

    const unsigned short* gA = A  + (size_t)(t0 + wave * 32 + sr) * 1024 + sc;
    const unsigned short* gB = Bt + (size_t)(n0 + wave * 16 + sr) * 1024 + sc;

    async16(gA,             &As[0][wave * 32][0]);
    async16(gA + 16 * 1024, &As[0][wave * 32 + 16][0]);
    async16(gB,             &Bs[0][wave * 16][0]);

    for (int kt = 0; kt < 32; ++kt) {
        const int cur = kt & 1;
        __syncthreads();
        if (kt < 31) {
            const int k1 = (kt + 1) * 32;
            async16(gA + k1,             &As[cur ^ 1][wave * 32][0]);
            async16(gA + k1 + 16 * 1024, &As[cur ^ 1][wave * 32 + 16][0]);
            async16(gB + k1,             &Bs[cur ^ 1][wave * 16][0]);
        }
        short8 af[4], bfr[2];
        for (int mt = 0; mt < 4; ++mt)
            af[mt] = *(const short8*)(&As[cur][wm * 64 + mt * 16 + l15][quad * 8]);
        for (int nt = 0; nt < 2; ++nt)
            bfr[nt] = *(const short8*)(&Bs[cur][wn * 32 + nt * 16 + l15][quad * 8]);
        for (int mt = 0; mt < 4; ++mt)
            for (int nt = 0; nt < 2; ++nt)
                acc[mt][nt] = __builtin_amdgcn_mfma_f32_16x16x32_bf16(bfr[nt], af[mt], acc[mt][nt], 0, 0, 0);
    }

    for (int mt = 0; mt < 4; ++mt) {
        const int t = t0 + wm * 64 + mt * 16 + l15;
        float* po = out_f + (size_t)t * 1024 + n0 + wn * 32;
        for (int nt = 0; nt < 2; ++nt) {
            float4 b4 = *(const float4*)(bias + n0 + wn * 32 + nt * 16 + quad * 4);
            float4 v = {acc[mt][nt][0] + b4.x, acc[mt][nt][1] + b4.y,
                        acc[mt][nt][2] + b4.z, acc[mt][nt][3] + b4.w};
            *(float4*)(po + nt * 16 + quad * 4) = v;
        }
    }
}

// ---------------- causal flash attention: 512 threads, 2 q-subtiles share K/V staging ----------------
// Per lane: one q-row (l15), keys along quad*4+r. Q pre-scaled by log2(e)/8 (exp2 domain).
__global__ __launch_bounds__(512)
void flash_kernel(const unsigned short* __restrict__ qkv,
                  const unsigned short* __restrict__ vT,
                  unsigned short* __restrict__ out) {
    __shared__ unsigned short Kt[2][64][72];     // [buf][key][d]
    __shared__ unsigned short Vt[2][64][72];     // [buf][d][key]
    __shared__ unsigned short Pt[8][16][72];     // per-wave P[qrow][key] bf16

    const int bh = blockIdx.x;                   // 0..31
    const int yy = blockIdx.y;                   // 0..15, zigzag long/short for per-CU balance
    const int qy = (yy & 1) ? (yy >> 1) : (15 - (yy >> 1));
    const int b = bh >> 4, h = bh & 15;
    const int tid = threadIdx.x;
    const int wave = tid >> 6, lane = tid & 63;
    const int group = wave >> 2, w4 = wave & 3;  // group 0: q-subtile 2qy, group 1: 2qy+1
    const int l15 = lane & 15, quad = lane >> 4;

    const int my_qt = 2 * qy + group;
    const int jmax  = 2 * qy + 1;

    const size_t rowb = (size_t)b * SS;

    short8 bq0, bq1;
    {
        const unsigned short* qp = qkv + (rowb + my_qt * 64 + w4 * 16 + l15) * 3072 + h * 64 + quad * 8;
        bq0 = *(const short8*)(qp);
        bq1 = *(const short8*)(qp + 32);
    }

    float l_i = 0.f;
    floatx4 o[4];
    for (int dt = 0; dt < 4; ++dt)
        for (int e = 0; e < 4; ++e) o[dt][e] = 0.f;

    const int qrow_l = w4 * 16 + l15;            // within the 64-row subtile

    // cooperative staging: 512 threads cover 64 rows x 64 cols in one shot (16B each)
    const int rr = tid >> 3, seg = (tid & 7) * 8;
    const unsigned short* kb = qkv + rowb * 3072 + 1024 + h * 64;
    const unsigned short* vb = vT + (size_t)bh * 64 * SS;
    int4 ka, va;

    #define PREF(j) { ka = *(const int4*)(kb + (size_t)((j) * 64 + rr) * 3072 + seg); \
                      va = *(const int4*)(vb + (size_t)rr * SS + (j) * 64 + seg); }
    #define STAGE(bf_) { *(int4*)(&Kt[bf_][rr][seg]) = ka; *(int4*)(&Vt[bf_][rr][seg]) = va; }

    PREF(0);
    STAGE(0);
    if (jmax > 0) PREF(1);

    for (int j = 0; j <= jmax; ++j) {
        const int cur = j & 1;
        __syncthreads();   // buf[cur] fully written; everyone done with buf[cur^1]
        if (j < jmax) {
            STAGE(cur ^ 1);
            if (j + 2 <= jmax) PREF(j + 2);
        }
        if (j > my_qt) continue;   // wave-uniform; no barriers below

        // S^T = K * Q^T : sc[nt][r] = S[qrow=l15][key = nt*16+quad*4+r] (log2 units)
        floatx4 sc[4];
        for (int nt = 0; nt < 4; ++nt)
            for (int e = 0; e < 4; ++e) sc[nt][e] = 0.f;
        for (int nt = 0; nt < 4; ++nt) {
            const unsigned short* kp = &Kt[cur][nt * 16 + l15][quad * 8];
            short8 ak0 = *(const short8*)(kp);
            short8 ak1 = *(const short8*)(kp + 32);
            sc[nt] = __builtin_amdgcn_mfma_f32_16x16x32_bf16(ak0, bq0, sc[nt], 0, 0, 0);
            sc[nt] = __builtin_amdgcn_mfma_f32_16x16x32_bf16(ak1, bq1, sc[nt], 0, 0, 0);
        }
        if (j == my_qt) {
            for (int nt = 0; nt < 4; ++nt)
                for (int r = 0; r < 4; ++r)
                    if (nt * 16 + quad * 4 + r > qrow_l) sc[nt][r] = -1.0e30f;
        }

        // fixed-max softmax: p = exp2(s), in-lane l accumulation
        for (int nt = 0; nt < 4; ++nt)
            for (int r = 0; r < 4; ++r) {
                float p = __builtin_amdgcn_exp2f(sc[nt][r]);
                sc[nt][r] = p;
                l_i += p;
            }

        // P^T as B-operand: packed write, contiguous read-back
        for (int nt = 0; nt < 4; ++nt) {
            uint2 w = {pack2bf(sc[nt][0], sc[nt][1]), pack2bf(sc[nt][2], sc[nt][3])};
            *(uint2*)(&Pt[wave][l15][nt * 16 + quad * 4]) = w;
        }
        asm volatile("s_waitcnt lgkmcnt(0)" ::: "memory");
        short8 bp0 = *(const short8*)(&Pt[wave][l15][quad * 8]);
        short8 bp1 = *(const short8*)(&Pt[wave][l15][32 + quad * 8]);
        for (int dt = 0; dt < 4; ++dt) {
            const unsigned short* vp = &Vt[cur][dt * 16 + l15][quad * 8];
            short8 av0 = *(const short8*)(vp);
            short8 av1 = *(const short8*)(vp + 32);
            o[dt] = __builtin_amdgcn_mfma_f32_16x16x32_bf16(av0, bp0, o[dt], 0, 0, 0);
            o[dt] = __builtin_amdgcn_mfma_f32_16x16x32_bf16(av1, bp1, o[dt], 0, 0, 0);
        }
    }
    #undef PREF
    #undef STAGE

    // final l reduce (cross-quad) + packed store; o[dt][r] = O[d=dt*16+quad*4+r][qrow=l15]
    l_i += __shfl_xor(l_i, 16);
    l_i += __shfl_xor(l_i, 32);
    float inv = 1.f / l_i;
    const int qrow = my_qt * 64 + w4 * 16 + l15;
    unsigned short* po = out + (rowb + qrow) * 1024 + h * 64;
    for (int dt = 0; dt < 4; ++dt) {
        uint2 w = {pack2bf(o[dt][0] * inv, o[dt][1] * inv),
                   pack2bf(o[dt][2] * inv, o[dt][3] * inv)};
        *(uint2*)(po + dt * 16 + quad * 4) = w;
    }
}

extern "C" void kernel_launch(void* const* d_in, const int* in_sizes, int n_in,
                              void* d_out, int out_size, void* d_ws, size_t ws_size,
                              hipStream_t stream) {
    const float* x        = (const float*)d_in[0];
    const float* c_attn_w = (const float*)d_in[1];
    const float* c_attn_b = (const float*)d_in[2];
    const float* c_proj_w = (const float*)d_in[3];
    const float* c_proj_b = (const float*)d_in[4];
    float* out = (float*)d_out;

    char* ws = (char*)d_ws;
    unsigned short* xb     = (unsigned short*)(ws);                      //  8 MB: [4096][1024]
    unsigned short* wqkvt  = (unsigned short*)(ws + 8388608);            //  6 MB: [3072][1024]
    unsigned short* wprojt = (unsigned short*)(ws + 14680064);           //  2 MB: [1024][1024]
    unsigned short* qkvb   = (unsigned short*)(ws + 16777216);           // 24 MB: [4096][3072]
    unsigned short* aout   = (unsigned short*)(ws + 41943040);           //  8 MB: [4096][1024]
    unsigned short* vT     = xb;  // aliases xb — dead after gemm1, vT written after

    prep_kernel<<<2048 + 3072 + 1024, 256, 0, stream>>>(x, c_attn_w, c_proj_w, xb, wqkvt, wprojt);
    gemm1_kernel<<<dim3(N3 / 128, TT / 128), 256, 0, stream>>>(xb, wqkvt, c_attn_b, qkvb);
    kv_aux_kernel<<<dim3(32, 32), 256, 0, stream>>>(qkvb, out, vT);
    flash_kernel<<<dim3(32, 16), 512, 0, stream>>>(qkvb, vT, aout);
    gemm2_kernel<<<dim3(DD / 64, TT / 128), 256, 0, stream>>>(aout, wprojt, c_proj_b, out);
}